// Round 10
// baseline (273.257 us; speedup 1.0000x reference)
//
#include <hip/hip_runtime.h>

static constexpr int HID = 32;
static constexpr int LEN = 32768;
static constexpr int NKL = 128;
static constexpr int HOP = 256;
#define SLOPE 0.2f

typedef short short8 __attribute__((ext_vector_type(8)));
typedef float floatx4 __attribute__((ext_vector_type(4)));
typedef unsigned int u32;

// ---------------- LDS map (main kernel) ----------------
//   [0, 17792)  xs_t: 278 rows x 64 B (32 bf16), XOR-swizzled (row&7)<<4
//               ys_t: rows 0..273, same layout/swizzle   [conv epi..LVC]
//   b2 weights NOT in LDS: streamed from kt into transient registers.
//   17792 B x 8 blocks = 142336 <= 163840  ->  8 blocks/CU = 32 waves/CU (HW cap)
static constexpr int XROW  = 64;
static constexpr int SMEMB = 17792;             // = 278 * 64

__device__ __forceinline__ int xsw(int row, int bcol) {
    return ((row << 6) + bcol) ^ ((row & 7) << 4);
}

// ---------------- workspace layout (ushort elements) ----------------
// kt  [16][128][64][96] bf16  (rows 192 B, 64 B-aligned)
// cwt [32][96] bf16
static constexpr int    B2COLS  = 96;
static constexpr int    B2SLAB  = 64 * B2COLS;        // 6144 ushorts / (b,kl)
static constexpr size_t KT_USH  = (size_t)16 * NKL * 64 * B2COLS;
static constexpr size_t CWT_OFF = KT_USH;             // total ws ~25.2 MB

__device__ __forceinline__ float leaky(float x) { return fmaxf(x, SLOPE * x); }

__device__ __forceinline__ unsigned short f2bf(float f) {
    union { float f; unsigned u; } v; v.f = f;
    unsigned r = v.u + 0x7FFFu + ((v.u >> 16) & 1u);   // RNE
    return (unsigned short)(r >> 16);
}
__device__ __forceinline__ u32 cvtpk(float lo, float hi) {
    u32 r;
    asm("v_cvt_pk_bf16_f32 %0, %1, %2" : "=v"(r) : "v"(lo), "v"(hi));
    return r;
}
__device__ __forceinline__ float rcp_fast(float x) {   // 1 ulp, inf->0 (exact limit)
    float r; asm("v_rcp_f32 %0, %1" : "=v"(r) : "v"(x)); return r;
}
// sigmoid(a)*tanh(c): tanh via 1 - 2/(1+e^{2c}); saturates correctly at +-inf
__device__ __forceinline__ float gatef(float a, float c) {
    float sg = rcp_fast(1.0f + __expf(-a));
    float t  = fmaf(-2.0f, rcp_fast(1.0f + __expf(2.0f * c)), 1.0f);
    return sg * t;
}

// =====================================================================================
// Pre-pass v3 (unchanged): kern [b][i][o][k][kl] f32 -> kt [b][kl][o][96] bf16,
// linearized 16 B stores.
// =====================================================================================
__global__ __launch_bounds__(256) void prep_kern(
    const float* __restrict__ kern,    // [16][32][64][3][128]
    const float* __restrict__ cw,      // [32][32][3]
    unsigned short* __restrict__ kt)   // workspace
{
    const int blk = blockIdx.x;        // 1024 = b*64 + o
    const int b = blk >> 6, o = blk & 63;
    const int tid = threadIdx.x;
    __shared__ unsigned short lt[32 * 386];    // [i][kk*128 + kl] bf16, row 386

    const float* src = kern + (size_t)(b * 2048 + o) * 384;
    #pragma unroll
    for (int j = 0; j < 12; ++j) {
        const int f = tid + 256 * j;           // float4 id < 3072
        const int i = f / 96, r = f - i * 96;
        float4 v = *(const float4*)(src + (size_t)i * 24576 + (size_t)r * 4);
        *(u32*)(lt + i * 386 + r * 4)     = cvtpk(v.x, v.y);
        *(u32*)(lt + i * 386 + r * 4 + 2) = cvtpk(v.z, v.w);
    }

    if (blk == 0) {   // conv weights -> cwt[o2][kk*32+i]
        #pragma unroll
        for (int j = 0; j < 12; ++j) {
            const int d = tid + 256 * j;       // < 3072
            const int o2 = d / 96, rr = d - o2 * 96;
            const int kk = rr >> 5, i = rr & 31;
            kt[CWT_OFF + d] = f2bf(cw[(o2 * 32 + i) * 3 + kk]);
        }
    }
    __syncthreads();

    // linear write-out: s in [0,1536) -> (kl = s/12, q = s%12); 16 B per store.
    unsigned short* slab = kt + (size_t)b * (NKL * 64 * B2COLS) + (size_t)o * B2COLS;
    #pragma unroll
    for (int j = 0; j < 6; ++j) {
        const int s = tid + 256 * j;           // < 1536 exactly
        const int kl = s / 12, q = s - kl * 12;
        const int kk = q >> 2;                 // cols 8q..8q+7 stay in one kk
        const int ib = 8 * (q & 3);            // i = ib..ib+7
        const unsigned short* p = lt + kk * 128 + kl;
        uint4 d;
        d.x = (u32)p[(ib + 0) * 386] | ((u32)p[(ib + 1) * 386] << 16);
        d.y = (u32)p[(ib + 2) * 386] | ((u32)p[(ib + 3) * 386] << 16);
        d.z = (u32)p[(ib + 4) * 386] | ((u32)p[(ib + 5) * 386] << 16);
        d.w = (u32)p[(ib + 6) * 386] | ((u32)p[(ib + 7) * 386] << 16);
        *(uint4*)(slab + (size_t)kl * B2SLAB + 8 * q) = d;
    }
}

// =====================================================================================
// Main kernel: 3 barriers, LDS 17792 B (8 blocks/CU possible). LVC phase restructured
// for low register pressure (R8/R9 post-mortem): #pragma unroll 1 pp loop stops the
// scheduler from hoisting both iterations' b2/h loads (was ~140 VGPR demand ->
// allocator collapse + scratch); qk-outer/T-inner keeps only 8 transient b2 regs +
// 8 named floatx4 accs live (~56-64 peak). launch_bounds(256,6): cap 85 -- lands
// <=64 -> 8 blocks/CU; 65..85 -> clean 4 blocks (no collapse).
// =====================================================================================
__global__ __launch_bounds__(256, 6) void univnet_mfma(
    const float* __restrict__ h,      // [16][32][32768]
    const float* __restrict__ bias,   // [16][64][128]
    const float* __restrict__ cb,     // [32]
    float* __restrict__ out,
    const unsigned short* __restrict__ kt)
{
    __shared__ __align__(16) char smem[SMEMB];

    const int blk = blockIdx.x;           // 2048
    const int b   = blk & 15;             // XCD-pinned: blk%8 == b%8
    const int kl  = blk >> 4;
    const int t0  = kl * HOP;
    const int p0  = t0 - 4;
    const int tid = threadIdx.x;
    const int w   = tid >> 6;
    const int lane = tid & 63;
    const int l15 = lane & 15;
    const int l4  = lane >> 4;

    const float* hb = h + (size_t)b * (HID * LEN);
    const bool edge = (kl == 0) || (kl == NKL - 1);

    // ---- prefetch conv-weight frags + biases (4 NAMED floats, no array) ----
    const unsigned short* cwt = kt + CWT_OFF;
    short8 b1f[2][3];
    #pragma unroll
    for (int tn = 0; tn < 2; ++tn)
        #pragma unroll
        for (int qk = 0; qk < 3; ++qk)
            b1f[tn][qk] = *(const short8*)(cwt + (tn * 16 + l15) * 96 + qk * 32 + l4 * 8);
    float4 cbq[2];
    cbq[0] = *(const float4*)(cb + l4 * 4);
    cbq[1] = *(const float4*)(cb + 16 + l4 * 4);
    const float bv0A = bias[((size_t)b * 64 + l15) * NKL + kl];
    const float bv0B = bias[((size_t)b * 64 + l15 + 32) * NKL + kl];
    const float bv1A = bias[((size_t)b * 64 + 16 + l15) * NKL + kl];
    const float bv1B = bias[((size_t)b * 64 + 16 + l15 + 32) * NKL + kl];

    // ================= Phase A: stage leaky(h) transposed, swizzled ================
    {
        auto stage = [&](int tau) {
            const int oct = tau & 3, cq = tau >> 2;
            u32 pk[4][4];
            if (!edge) {
                #pragma unroll
                for (int jp = 0; jp < 4; ++jp) {
                    const int i0 = oct * 8 + 2 * jp;
                    float4 f0 = *(const float4*)(hb + (size_t)i0 * LEN + p0 + 4 * cq);
                    float4 f1 = *(const float4*)(hb + (size_t)(i0 + 1) * LEN + p0 + 4 * cq);
                    pk[0][jp] = cvtpk(leaky(f0.x), leaky(f1.x));
                    pk[1][jp] = cvtpk(leaky(f0.y), leaky(f1.y));
                    pk[2][jp] = cvtpk(leaky(f0.z), leaky(f1.z));
                    pk[3][jp] = cvtpk(leaky(f0.w), leaky(f1.w));
                }
            } else {
                #pragma unroll
                for (int jp = 0; jp < 4; ++jp) {
                    const int i0 = oct * 8 + 2 * jp;
                    #pragma unroll
                    for (int e = 0; e < 4; ++e) {
                        const int p = p0 + 4 * cq + e;
                        float a = 0.0f, c2 = 0.0f;
                        if ((unsigned)p < (unsigned)LEN) {
                            a  = hb[(size_t)i0 * LEN + p];
                            c2 = hb[(size_t)(i0 + 1) * LEN + p];
                        }
                        pk[e][jp] = cvtpk(leaky(a), leaky(c2));
                    }
                }
            }
            #pragma unroll
            for (int e = 0; e < 4; ++e)
                *(uint4*)(smem + xsw(4 * cq + e, oct * 16)) =
                    make_uint4(pk[e][0], pk[e][1], pk[e][2], pk[e][3]);
        };
        stage(tid);
        if (tid < 8) stage(256 + tid);
        // zero pad rows 264..277 (bytes [16896, 17792))
        if (tid < 224) ((u32*)(smem + 16896))[tid] = 0u;
    }

    __syncthreads();   // s0: xs_t ready

    // ================= Conv GEMM (operand-swapped => C^T layout) ====================
    floatx4 cacc[9];
    #pragma unroll
    for (int n = 0; n < 9; ++n) {
        const int tt = w + 4 * n;
        if (tt < 34) {
            const int tm = tt >> 1, tn = tt & 1;
            short8 af[3];
            #pragma unroll
            for (int qk = 0; qk < 3; ++qk)
                af[qk] = *(const short8*)(smem + xsw(tm * 16 + l15 + 3 * qk, l4 * 16));
            floatx4 acc = {cbq[tn].x, cbq[tn].y, cbq[tn].z, cbq[tn].w};
            #pragma unroll
            for (int qk = 0; qk < 3; ++qk)
                acc = __builtin_amdgcn_mfma_f32_16x16x32_bf16(b1f[tn][qk], af[qk], acc, 0, 0, 0);
            cacc[n] = acc;
        }
    }
    __syncthreads();   // s1: conv reads done; xs_t dead

    // ---- conv epilogue: cvt_pk pair + one 8-B store per tile, swizzled ----
    #pragma unroll
    for (int n = 0; n < 9; ++n) {
        const int tt = w + 4 * n;
        if (tt < 34) {
            const int tm = tt >> 1, tn = tt & 1;
            const int c_out = tm * 16 + l15;
            const int p = t0 - 1 + c_out;
            u32 q0 = 0u, q1 = 0u;
            if ((unsigned)p < (unsigned)LEN) {
                q0 = cvtpk(leaky(cacc[n][0]), leaky(cacc[n][1]));
                q1 = cvtpk(leaky(cacc[n][2]), leaky(cacc[n][3]));
            }
            *(uint2*)(smem + xsw(c_out, tn * 32 + l4 * 8)) = make_uint2(q0, q1);
        }
    }
    __syncthreads();   // s2: ys_t ready (last barrier)

    // ===== LVC GEMM fused with output, low-pressure schedule =====
    // Real loop over pp (no unroll => no cross-iteration hoisting). Within a pp:
    // qk-outer streams 2 transient b2 frags through 8 MFMAs into 8 named accs;
    // then per-T: h load -> gate -> store (declining pressure, TLP hides latency).
    const unsigned short* b2s = kt + (size_t)(b * NKL + kl) * B2SLAB;   // [o][96]
    #pragma unroll 1
    for (int pp = 0; pp < 2; ++pp) {
        const int oA = pp * 16 + l15;
        const float bA = pp ? bv1A : bv0A;
        const float bB = pp ? bv1B : bv0B;
        floatx4 aA0 = {bA, bA, bA, bA}, aA1 = aA0, aA2 = aA0, aA3 = aA0;
        floatx4 aB0 = {bB, bB, bB, bB}, aB1 = aB0, aB2 = aB0, aB3 = aB0;
        const unsigned short* rA = b2s + oA * B2COLS + l4 * 8;          // row oA
        const unsigned short* rB = rA + 32 * B2COLS;                    // row oA+32
        #pragma unroll
        for (int qk = 0; qk < 3; ++qk) {
            const short8 b2A = *(const short8*)(rA + 32 * qk);
            const short8 b2B = *(const short8*)(rB + 32 * qk);
            short8 af;
            af  = *(const short8*)(smem + xsw((w)      * 16 + l15 + qk, l4 * 16));
            aA0 = __builtin_amdgcn_mfma_f32_16x16x32_bf16(af, b2A, aA0, 0, 0, 0);
            aB0 = __builtin_amdgcn_mfma_f32_16x16x32_bf16(af, b2B, aB0, 0, 0, 0);
            af  = *(const short8*)(smem + xsw((4 + w)  * 16 + l15 + qk, l4 * 16));
            aA1 = __builtin_amdgcn_mfma_f32_16x16x32_bf16(af, b2A, aA1, 0, 0, 0);
            aB1 = __builtin_amdgcn_mfma_f32_16x16x32_bf16(af, b2B, aB1, 0, 0, 0);
            af  = *(const short8*)(smem + xsw((8 + w)  * 16 + l15 + qk, l4 * 16));
            aA2 = __builtin_amdgcn_mfma_f32_16x16x32_bf16(af, b2A, aA2, 0, 0, 0);
            aB2 = __builtin_amdgcn_mfma_f32_16x16x32_bf16(af, b2B, aB2, 0, 0, 0);
            af  = *(const short8*)(smem + xsw((12 + w) * 16 + l15 + qk, l4 * 16));
            aA3 = __builtin_amdgcn_mfma_f32_16x16x32_bf16(af, b2A, aA3, 0, 0, 0);
            aB3 = __builtin_amdgcn_mfma_f32_16x16x32_bf16(af, b2B, aB3, 0, 0, 0);
        }
        const float* hrow = hb + (size_t)oA * LEN + t0 + w * 16 + l4 * 4;
        float* orow = out + ((size_t)b * HID + oA) * LEN + t0 + w * 16 + l4 * 4;
#define EPI_T(T, AA, BB)                                                        \
        {                                                                       \
            const float4 hv = *(const float4*)(hrow + (T) * 64);                \
            float4 ov;                                                          \
            ov.x = hv.x + gatef(AA[0], BB[0]);                                  \
            ov.y = hv.y + gatef(AA[1], BB[1]);                                  \
            ov.z = hv.z + gatef(AA[2], BB[2]);                                  \
            ov.w = hv.w + gatef(AA[3], BB[3]);                                  \
            *(float4*)(orow + (T) * 64) = ov;                                   \
        }
        EPI_T(0, aA0, aB0)
        EPI_T(1, aA1, aB1)
        EPI_T(2, aA2, aB2)
        EPI_T(3, aA3, aB3)
#undef EPI_T
    }
    // kernel ends: stores fire-and-forget, no tail barrier
}

extern "C" void kernel_launch(void* const* d_in, const int* in_sizes, int n_in,
                              void* d_out, int out_size, void* d_ws, size_t ws_size,
                              hipStream_t stream) {
    const float* h    = (const float*)d_in[0];
    const float* kern = (const float*)d_in[1];
    const float* bias = (const float*)d_in[2];
    const float* cw   = (const float*)d_in[3];
    const float* cb   = (const float*)d_in[4];
    float* outp = (float*)d_out;
    unsigned short* kt = (unsigned short*)d_ws;   // ~25.2 MB workspace

    prep_kern<<<1024, 256, 0, stream>>>(kern, cw, kt);
    univnet_mfma<<<2048, 256, 0, stream>>>(h, bias, cb, outp, kt);
}

// Round 11
// 246.631 us; speedup vs baseline: 1.1080x; 1.1080x over previous
//
#include <hip/hip_runtime.h>

static constexpr int HID = 32;
static constexpr int LEN = 32768;
static constexpr int NKL = 128;
static constexpr int HOP = 256;
#define SLOPE 0.2f

typedef short short8 __attribute__((ext_vector_type(8)));
typedef float floatx4 __attribute__((ext_vector_type(4)));
typedef unsigned int u32;

// ---------------- LDS map (main kernel) ----------------
//   [0, 17792)  xs_t: 278 rows x 64 B (32 bf16), XOR-swizzled (row&7)<<4
//               ys_t: rows 0..273, same layout/swizzle   [conv epi..LVC]
//   b2 weights NOT in LDS: streamed from kt into transient registers.
static constexpr int XROW  = 64;
static constexpr int SMEMB = 17792;             // = 278 * 64

__device__ __forceinline__ int xsw(int row, int bcol) {
    return ((row << 6) + bcol) ^ ((row & 7) << 4);
}

// ---------------- workspace layout (ushort elements) ----------------
// kt  [16][128][64][96] bf16  (rows 192 B, 64 B-aligned)
// cwt [32][96] bf16
static constexpr int    B2COLS  = 96;
static constexpr int    B2SLAB  = 64 * B2COLS;        // 6144 ushorts / (b,kl)
static constexpr size_t KT_USH  = (size_t)16 * NKL * 64 * B2COLS;
static constexpr size_t CWT_OFF = KT_USH;             // total ws ~25.2 MB

__device__ __forceinline__ float leaky(float x) { return fmaxf(x, SLOPE * x); }

__device__ __forceinline__ unsigned short f2bf(float f) {
    union { float f; unsigned u; } v; v.f = f;
    unsigned r = v.u + 0x7FFFu + ((v.u >> 16) & 1u);   // RNE
    return (unsigned short)(r >> 16);
}
__device__ __forceinline__ u32 cvtpk(float lo, float hi) {
    u32 r;
    asm("v_cvt_pk_bf16_f32 %0, %1, %2" : "=v"(r) : "v"(lo), "v"(hi));
    return r;
}
__device__ __forceinline__ float rcp_fast(float x) {   // 1 ulp, inf->0 (exact limit)
    float r; asm("v_rcp_f32 %0, %1" : "=v"(r) : "v"(x)); return r;
}
// sigmoid(a)*tanh(c): tanh via 1 - 2/(1+e^{2c}); saturates correctly at +-inf
__device__ __forceinline__ float gatef(float a, float c) {
    float sg = rcp_fast(1.0f + __expf(-a));
    float t  = fmaf(-2.0f, rcp_fast(1.0f + __expf(2.0f * c)), 1.0f);
    return sg * t;
}

// =====================================================================================
// Pre-pass v3 (unchanged): kern [b][i][o][k][kl] f32 -> kt [b][kl][o][96] bf16,
// linearized 16 B stores.
// =====================================================================================
__global__ __launch_bounds__(256) void prep_kern(
    const float* __restrict__ kern,    // [16][32][64][3][128]
    const float* __restrict__ cw,      // [32][32][3]
    unsigned short* __restrict__ kt)   // workspace
{
    const int blk = blockIdx.x;        // 1024 = b*64 + o
    const int b = blk >> 6, o = blk & 63;
    const int tid = threadIdx.x;
    __shared__ unsigned short lt[32 * 386];    // [i][kk*128 + kl] bf16, row 386

    const float* src = kern + (size_t)(b * 2048 + o) * 384;
    #pragma unroll
    for (int j = 0; j < 12; ++j) {
        const int f = tid + 256 * j;           // float4 id < 3072
        const int i = f / 96, r = f - i * 96;
        float4 v = *(const float4*)(src + (size_t)i * 24576 + (size_t)r * 4);
        *(u32*)(lt + i * 386 + r * 4)     = cvtpk(v.x, v.y);
        *(u32*)(lt + i * 386 + r * 4 + 2) = cvtpk(v.z, v.w);
    }

    if (blk == 0) {   // conv weights -> cwt[o2][kk*32+i]
        #pragma unroll
        for (int j = 0; j < 12; ++j) {
            const int d = tid + 256 * j;       // < 3072
            const int o2 = d / 96, rr = d - o2 * 96;
            const int kk = rr >> 5, i = rr & 31;
            kt[CWT_OFF + d] = f2bf(cw[(o2 * 32 + i) * 3 + kk]);
        }
    }
    __syncthreads();

    // linear write-out: s in [0,1536) -> (kl = s/12, q = s%12); 16 B per store.
    unsigned short* slab = kt + (size_t)b * (NKL * 64 * B2COLS) + (size_t)o * B2COLS;
    #pragma unroll
    for (int j = 0; j < 6; ++j) {
        const int s = tid + 256 * j;           // < 1536 exactly
        const int kl = s / 12, q = s - kl * 12;
        const int kk = q >> 2;                 // cols 8q..8q+7 stay in one kk
        const int ib = 8 * (q & 3);            // i = ib..ib+7
        const unsigned short* p = lt + kk * 128 + kl;
        uint4 d;
        d.x = (u32)p[(ib + 0) * 386] | ((u32)p[(ib + 1) * 386] << 16);
        d.y = (u32)p[(ib + 2) * 386] | ((u32)p[(ib + 3) * 386] << 16);
        d.z = (u32)p[(ib + 4) * 386] | ((u32)p[(ib + 5) * 386] << 16);
        d.w = (u32)p[(ib + 6) * 386] | ((u32)p[(ib + 7) * 386] << 16);
        *(uint4*)(slab + (size_t)kl * B2SLAB + 8 * q) = d;
    }
}

// =====================================================================================
// Main kernel: 3 barriers, LDS 17792 B, low-pressure LVC schedule (R10 body).
// __launch_bounds__(256,5): cap 102 total regs -- the proven-safe setting (R2/R7
// compiled healthy at 48 arch; R8/R9/R10 proved any cap <102 collapses this body to
// spill-everything). If the R10 restructure's demand lands <=~84 total, HW gives
// 6 waves/EU naturally; worst case it matches R7's 5 waves. No spill either way.
// =====================================================================================
__global__ __launch_bounds__(256, 5) void univnet_mfma(
    const float* __restrict__ h,      // [16][32][32768]
    const float* __restrict__ bias,   // [16][64][128]
    const float* __restrict__ cb,     // [32]
    float* __restrict__ out,
    const unsigned short* __restrict__ kt)
{
    __shared__ __align__(16) char smem[SMEMB];

    const int blk = blockIdx.x;           // 2048
    const int b   = blk & 15;             // XCD-pinned: blk%8 == b%8
    const int kl  = blk >> 4;
    const int t0  = kl * HOP;
    const int p0  = t0 - 4;
    const int tid = threadIdx.x;
    const int w   = tid >> 6;
    const int lane = tid & 63;
    const int l15 = lane & 15;
    const int l4  = lane >> 4;

    const float* hb = h + (size_t)b * (HID * LEN);
    const bool edge = (kl == 0) || (kl == NKL - 1);

    // ---- prefetch conv-weight frags + biases (4 NAMED floats, no array) ----
    const unsigned short* cwt = kt + CWT_OFF;
    short8 b1f[2][3];
    #pragma unroll
    for (int tn = 0; tn < 2; ++tn)
        #pragma unroll
        for (int qk = 0; qk < 3; ++qk)
            b1f[tn][qk] = *(const short8*)(cwt + (tn * 16 + l15) * 96 + qk * 32 + l4 * 8);
    float4 cbq[2];
    cbq[0] = *(const float4*)(cb + l4 * 4);
    cbq[1] = *(const float4*)(cb + 16 + l4 * 4);
    const float bv0A = bias[((size_t)b * 64 + l15) * NKL + kl];
    const float bv0B = bias[((size_t)b * 64 + l15 + 32) * NKL + kl];
    const float bv1A = bias[((size_t)b * 64 + 16 + l15) * NKL + kl];
    const float bv1B = bias[((size_t)b * 64 + 16 + l15 + 32) * NKL + kl];

    // ================= Phase A: stage leaky(h) transposed, swizzled ================
    {
        auto stage = [&](int tau) {
            const int oct = tau & 3, cq = tau >> 2;
            u32 pk[4][4];
            if (!edge) {
                #pragma unroll
                for (int jp = 0; jp < 4; ++jp) {
                    const int i0 = oct * 8 + 2 * jp;
                    float4 f0 = *(const float4*)(hb + (size_t)i0 * LEN + p0 + 4 * cq);
                    float4 f1 = *(const float4*)(hb + (size_t)(i0 + 1) * LEN + p0 + 4 * cq);
                    pk[0][jp] = cvtpk(leaky(f0.x), leaky(f1.x));
                    pk[1][jp] = cvtpk(leaky(f0.y), leaky(f1.y));
                    pk[2][jp] = cvtpk(leaky(f0.z), leaky(f1.z));
                    pk[3][jp] = cvtpk(leaky(f0.w), leaky(f1.w));
                }
            } else {
                #pragma unroll
                for (int jp = 0; jp < 4; ++jp) {
                    const int i0 = oct * 8 + 2 * jp;
                    #pragma unroll
                    for (int e = 0; e < 4; ++e) {
                        const int p = p0 + 4 * cq + e;
                        float a = 0.0f, c2 = 0.0f;
                        if ((unsigned)p < (unsigned)LEN) {
                            a  = hb[(size_t)i0 * LEN + p];
                            c2 = hb[(size_t)(i0 + 1) * LEN + p];
                        }
                        pk[e][jp] = cvtpk(leaky(a), leaky(c2));
                    }
                }
            }
            #pragma unroll
            for (int e = 0; e < 4; ++e)
                *(uint4*)(smem + xsw(4 * cq + e, oct * 16)) =
                    make_uint4(pk[e][0], pk[e][1], pk[e][2], pk[e][3]);
        };
        stage(tid);
        if (tid < 8) stage(256 + tid);
        // zero pad rows 264..277 (bytes [16896, 17792))
        if (tid < 224) ((u32*)(smem + 16896))[tid] = 0u;
    }

    __syncthreads();   // s0: xs_t ready

    // ================= Conv GEMM (operand-swapped => C^T layout) ====================
    floatx4 cacc[9];
    #pragma unroll
    for (int n = 0; n < 9; ++n) {
        const int tt = w + 4 * n;
        if (tt < 34) {
            const int tm = tt >> 1, tn = tt & 1;
            short8 af[3];
            #pragma unroll
            for (int qk = 0; qk < 3; ++qk)
                af[qk] = *(const short8*)(smem + xsw(tm * 16 + l15 + 3 * qk, l4 * 16));
            floatx4 acc = {cbq[tn].x, cbq[tn].y, cbq[tn].z, cbq[tn].w};
            #pragma unroll
            for (int qk = 0; qk < 3; ++qk)
                acc = __builtin_amdgcn_mfma_f32_16x16x32_bf16(b1f[tn][qk], af[qk], acc, 0, 0, 0);
            cacc[n] = acc;
        }
    }
    __syncthreads();   // s1: conv reads done; xs_t dead

    // ---- conv epilogue: cvt_pk pair + one 8-B store per tile, swizzled ----
    #pragma unroll
    for (int n = 0; n < 9; ++n) {
        const int tt = w + 4 * n;
        if (tt < 34) {
            const int tm = tt >> 1, tn = tt & 1;
            const int c_out = tm * 16 + l15;
            const int p = t0 - 1 + c_out;
            u32 q0 = 0u, q1 = 0u;
            if ((unsigned)p < (unsigned)LEN) {
                q0 = cvtpk(leaky(cacc[n][0]), leaky(cacc[n][1]));
                q1 = cvtpk(leaky(cacc[n][2]), leaky(cacc[n][3]));
            }
            *(uint2*)(smem + xsw(c_out, tn * 32 + l4 * 8)) = make_uint2(q0, q1);
        }
    }
    __syncthreads();   // s2: ys_t ready (last barrier)

    // ===== LVC GEMM fused with output, low-pressure schedule =====
    // Real loop over pp (no unroll => no cross-iteration hoisting). Within a pp:
    // qk-outer streams 2 transient b2 frags through 8 MFMAs into 8 named accs;
    // then per-T: h load -> gate -> store (declining pressure, TLP hides latency).
    const unsigned short* b2s = kt + (size_t)(b * NKL + kl) * B2SLAB;   // [o][96]
    #pragma unroll 1
    for (int pp = 0; pp < 2; ++pp) {
        const int oA = pp * 16 + l15;
        const float bA = pp ? bv1A : bv0A;
        const float bB = pp ? bv1B : bv0B;
        floatx4 aA0 = {bA, bA, bA, bA}, aA1 = aA0, aA2 = aA0, aA3 = aA0;
        floatx4 aB0 = {bB, bB, bB, bB}, aB1 = aB0, aB2 = aB0, aB3 = aB0;
        const unsigned short* rA = b2s + oA * B2COLS + l4 * 8;          // row oA
        const unsigned short* rB = rA + 32 * B2COLS;                    // row oA+32
        #pragma unroll
        for (int qk = 0; qk < 3; ++qk) {
            const short8 b2A = *(const short8*)(rA + 32 * qk);
            const short8 b2B = *(const short8*)(rB + 32 * qk);
            short8 af;
            af  = *(const short8*)(smem + xsw((w)      * 16 + l15 + qk, l4 * 16));
            aA0 = __builtin_amdgcn_mfma_f32_16x16x32_bf16(af, b2A, aA0, 0, 0, 0);
            aB0 = __builtin_amdgcn_mfma_f32_16x16x32_bf16(af, b2B, aB0, 0, 0, 0);
            af  = *(const short8*)(smem + xsw((4 + w)  * 16 + l15 + qk, l4 * 16));
            aA1 = __builtin_amdgcn_mfma_f32_16x16x32_bf16(af, b2A, aA1, 0, 0, 0);
            aB1 = __builtin_amdgcn_mfma_f32_16x16x32_bf16(af, b2B, aB1, 0, 0, 0);
            af  = *(const short8*)(smem + xsw((8 + w)  * 16 + l15 + qk, l4 * 16));
            aA2 = __builtin_amdgcn_mfma_f32_16x16x32_bf16(af, b2A, aA2, 0, 0, 0);
            aB2 = __builtin_amdgcn_mfma_f32_16x16x32_bf16(af, b2B, aB2, 0, 0, 0);
            af  = *(const short8*)(smem + xsw((12 + w) * 16 + l15 + qk, l4 * 16));
            aA3 = __builtin_amdgcn_mfma_f32_16x16x32_bf16(af, b2A, aA3, 0, 0, 0);
            aB3 = __builtin_amdgcn_mfma_f32_16x16x32_bf16(af, b2B, aB3, 0, 0, 0);
        }
        const float* hrow = hb + (size_t)oA * LEN + t0 + w * 16 + l4 * 4;
        float* orow = out + ((size_t)b * HID + oA) * LEN + t0 + w * 16 + l4 * 4;
#define EPI_T(T, AA, BB)                                                        \
        {                                                                       \
            const float4 hv = *(const float4*)(hrow + (T) * 64);                \
            float4 ov;                                                          \
            ov.x = hv.x + gatef(AA[0], BB[0]);                                  \
            ov.y = hv.y + gatef(AA[1], BB[1]);                                  \
            ov.z = hv.z + gatef(AA[2], BB[2]);                                  \
            ov.w = hv.w + gatef(AA[3], BB[3]);                                  \
            *(float4*)(orow + (T) * 64) = ov;                                   \
        }
        EPI_T(0, aA0, aB0)
        EPI_T(1, aA1, aB1)
        EPI_T(2, aA2, aB2)
        EPI_T(3, aA3, aB3)
#undef EPI_T
    }
    // kernel ends: stores fire-and-forget, no tail barrier
}

extern "C" void kernel_launch(void* const* d_in, const int* in_sizes, int n_in,
                              void* d_out, int out_size, void* d_ws, size_t ws_size,
                              hipStream_t stream) {
    const float* h    = (const float*)d_in[0];
    const float* kern = (const float*)d_in[1];
    const float* bias = (const float*)d_in[2];
    const float* cw   = (const float*)d_in[3];
    const float* cb   = (const float*)d_in[4];
    float* outp = (float*)d_out;
    unsigned short* kt = (unsigned short*)d_ws;   // ~25.2 MB workspace

    prep_kern<<<1024, 256, 0, stream>>>(kern, cw, kt);
    univnet_mfma<<<2048, 256, 0, stream>>>(h, bias, cb, outp, kt);
}

// Round 12
// 216.195 us; speedup vs baseline: 1.2639x; 1.1408x over previous
//
#include <hip/hip_runtime.h>

static constexpr int HID = 32;
static constexpr int LEN = 32768;
static constexpr int NKL = 128;
static constexpr int HOP = 256;
#define SLOPE 0.2f

typedef short short8 __attribute__((ext_vector_type(8)));
typedef float floatx4 __attribute__((ext_vector_type(4)));
typedef unsigned int u32;

// ---------------- LDS map (main kernel), one __shared__ char arena ----------------
//   [0, 17792)       xs_t: 278 rows x 64 B (32 bf16), XOR-swizzled (row&7)<<4
//                    ys_t: rows 0..273, same layout/swizzle   [conv epi..LVC]
//   [17792, 31104)   b2: LVC weights [o(64)][104 bf16] (208 B row), linear
//   (no os buffer: gates go straight from registers to global)
// NOTE (R8-R11 post-mortem): every attempt to shrink LDS + move b2 to registers or
// raise the launch-bounds wave target collapsed the allocator to spill-everything
// (VGPR 32-48 / SGPR 32, +50..140 MB scratch traffic). This configuration --
// b2 via global_load_lds, cap 102 (256,5) -- is the only family that compiles
// healthy (48 VGPR / 112 SGPR, zero scratch). It is the verified optimum.
static constexpr int XROW  = 64;
static constexpr int WOFF  = 17792;             // = 278 * 64
static constexpr int WROW  = 208;
static constexpr int WSLAB = 64 * WROW;         // 13312 = 13 x 1024 gload_lds chunks
static constexpr int SMEMB = WOFF + WSLAB;      // 31104 -> 5 blocks/CU

__device__ __forceinline__ int xsw(int row, int bcol) {
    return ((row << 6) + bcol) ^ ((row & 7) << 4);
}

// ---------------- workspace layout (ushort elements) ----------------
static constexpr size_t KT_USH  = (size_t)16 * NKL * 64 * 104;
static constexpr size_t CWT_OFF = KT_USH;

__device__ __forceinline__ float leaky(float x) { return fmaxf(x, SLOPE * x); }

__device__ __forceinline__ unsigned short f2bf(float f) {
    union { float f; unsigned u; } v; v.f = f;
    unsigned r = v.u + 0x7FFFu + ((v.u >> 16) & 1u);   // RNE
    return (unsigned short)(r >> 16);
}
__device__ __forceinline__ u32 cvtpk(float lo, float hi) {
    u32 r;
    asm("v_cvt_pk_bf16_f32 %0, %1, %2" : "=v"(r) : "v"(lo), "v"(hi));
    return r;
}
__device__ __forceinline__ float rcp_fast(float x) {   // 1 ulp, inf->0 (exact limit)
    float r; asm("v_rcp_f32 %0, %1" : "=v"(r) : "v"(x)); return r;
}
// sigmoid(a)*tanh(c): tanh via 1 - 2/(1+e^{2c}); saturates correctly at +-inf
__device__ __forceinline__ float gatef(float a, float c) {
    float sg = rcp_fast(1.0f + __expf(-a));
    float t  = fmaf(-2.0f, rcp_fast(1.0f + __expf(2.0f * c)), 1.0f);
    return sg * t;
}

// =====================================================================================
// Pre-pass v2: kern [b][i][o][k][kl] f32 -> kt [b][kl][o][104] bf16, linearized stores
// =====================================================================================
__global__ __launch_bounds__(256) void prep_kern(
    const float* __restrict__ kern,    // [16][32][64][3][128]
    const float* __restrict__ cw,      // [32][32][3]
    unsigned short* __restrict__ kt)   // workspace
{
    const int blk = blockIdx.x;        // 1024 = b*64 + o
    const int b = blk >> 6, o = blk & 63;
    const int tid = threadIdx.x;
    __shared__ unsigned short lt[32 * 386];    // [i][kk*128 + kl] bf16, row 386

    const float* src = kern + (size_t)(b * 2048 + o) * 384;
    #pragma unroll
    for (int j = 0; j < 12; ++j) {
        const int f = tid + 256 * j;           // float4 id < 3072
        const int i = f / 96, r = f - i * 96;
        float4 v = *(const float4*)(src + (size_t)i * 24576 + (size_t)r * 4);
        *(u32*)(lt + i * 386 + r * 4)     = cvtpk(v.x, v.y);
        *(u32*)(lt + i * 386 + r * 4 + 2) = cvtpk(v.z, v.w);
    }

    if (blk == 0) {   // conv weights -> cwt[o2][kk*32+i]
        #pragma unroll
        for (int j = 0; j < 12; ++j) {
            const int d = tid + 256 * j;       // < 3072
            const int o2 = d / 96, rr = d - o2 * 96;
            const int kk = rr >> 5, i = rr & 31;
            kt[CWT_OFF + d] = f2bf(cw[(o2 * 32 + i) * 3 + kk]);
        }
    }
    __syncthreads();

    unsigned short* slab = kt + (size_t)b * (NKL * 64 * 104) + (size_t)o * 104;
    #pragma unroll
    for (int j = 0; j < 7; ++j) {
        const int s = tid + 256 * j;           // < 1792, guard at 1664
        if (s < 1664) {
            const int kl = s / 13, q = s - kl * 13;
            uint4 d = make_uint4(0u, 0u, 0u, 0u);
            if (q < 12) {
                const int kk = q >> 2;
                const int ib = 8 * (q & 3);
                const unsigned short* p = lt + kk * 128 + kl;
                d.x = (u32)p[(ib + 0) * 386] | ((u32)p[(ib + 1) * 386] << 16);
                d.y = (u32)p[(ib + 2) * 386] | ((u32)p[(ib + 3) * 386] << 16);
                d.z = (u32)p[(ib + 4) * 386] | ((u32)p[(ib + 5) * 386] << 16);
                d.w = (u32)p[(ib + 6) * 386] | ((u32)p[(ib + 7) * 386] << 16);
            }
            *(uint4*)(slab + (size_t)kl * 6656 + 8 * q) = d;
        }
    }
}

// =====================================================================================
// Main kernel: 3 barriers. Back half fused: LVC MFMA -> gate(f32) -> +h -> store,
// all in registers. Verified 81.0 us (R7).
// =====================================================================================
__global__ __launch_bounds__(256, 5) void univnet_mfma(
    const float* __restrict__ h,      // [16][32][32768]
    const float* __restrict__ bias,   // [16][64][128]
    const float* __restrict__ cb,     // [32]
    float* __restrict__ out,
    const unsigned short* __restrict__ kt)
{
    __shared__ __align__(16) char smem[SMEMB];

    const int blk = blockIdx.x;           // 2048
    const int b   = blk & 15;             // XCD-pinned: blk%8 == b%8
    const int kl  = blk >> 4;
    const int t0  = kl * HOP;
    const int p0  = t0 - 4;
    const int tid = threadIdx.x;
    const int w   = tid >> 6;
    const int lane = tid & 63;
    const int l15 = lane & 15;
    const int l4  = lane >> 4;

    const float* hb = h + (size_t)b * (HID * LEN);
    const bool edge = (kl == 0) || (kl == NKL - 1);

    // ---- async-stage LVC weight slab into LDS (linear dest, drained at s0) ----
    {
        const char* slab = (const char*)kt + (size_t)(b * NKL + kl) * WSLAB;
        #pragma unroll
        for (int j = 0; j < 4; ++j) {
            const int c = w + 4 * j;
            if (c < 13)
                __builtin_amdgcn_global_load_lds(
                    (const u32 __attribute__((address_space(1)))*)(slab + c * 1024 + lane * 16),
                    (u32 __attribute__((address_space(3)))*)(smem + WOFF + c * 1024),
                    16, 0, 0);
        }
    }

    // ---- prefetch conv-weight frags + biases ----
    const unsigned short* cwt = kt + CWT_OFF;
    short8 b1f[2][3];
    #pragma unroll
    for (int tn = 0; tn < 2; ++tn)
        #pragma unroll
        for (int qk = 0; qk < 3; ++qk)
            b1f[tn][qk] = *(const short8*)(cwt + (tn * 16 + l15) * 96 + qk * 32 + l4 * 8);
    float4 cbq[2];
    cbq[0] = *(const float4*)(cb + l4 * 4);
    cbq[1] = *(const float4*)(cb + 16 + l4 * 4);
    float bv[2][2];
    #pragma unroll
    for (int pp = 0; pp < 2; ++pp) {
        bv[pp][0] = bias[((size_t)b * 64 + pp * 16 + l15) * NKL + kl];
        bv[pp][1] = bias[((size_t)b * 64 + pp * 16 + l15 + 32) * NKL + kl];
    }

    // ================= Phase A: stage leaky(h) transposed, swizzled ================
    {
        auto stage = [&](int tau) {
            const int oct = tau & 3, cq = tau >> 2;
            u32 pk[4][4];
            if (!edge) {
                #pragma unroll
                for (int jp = 0; jp < 4; ++jp) {
                    const int i0 = oct * 8 + 2 * jp;
                    float4 f0 = *(const float4*)(hb + (size_t)i0 * LEN + p0 + 4 * cq);
                    float4 f1 = *(const float4*)(hb + (size_t)(i0 + 1) * LEN + p0 + 4 * cq);
                    pk[0][jp] = cvtpk(leaky(f0.x), leaky(f1.x));
                    pk[1][jp] = cvtpk(leaky(f0.y), leaky(f1.y));
                    pk[2][jp] = cvtpk(leaky(f0.z), leaky(f1.z));
                    pk[3][jp] = cvtpk(leaky(f0.w), leaky(f1.w));
                }
            } else {
                #pragma unroll
                for (int jp = 0; jp < 4; ++jp) {
                    const int i0 = oct * 8 + 2 * jp;
                    #pragma unroll
                    for (int e = 0; e < 4; ++e) {
                        const int p = p0 + 4 * cq + e;
                        float a = 0.0f, c2 = 0.0f;
                        if ((unsigned)p < (unsigned)LEN) {
                            a  = hb[(size_t)i0 * LEN + p];
                            c2 = hb[(size_t)(i0 + 1) * LEN + p];
                        }
                        pk[e][jp] = cvtpk(leaky(a), leaky(c2));
                    }
                }
            }
            #pragma unroll
            for (int e = 0; e < 4; ++e)
                *(uint4*)(smem + xsw(4 * cq + e, oct * 16)) =
                    make_uint4(pk[e][0], pk[e][1], pk[e][2], pk[e][3]);
        };
        stage(tid);
        if (tid < 8) stage(256 + tid);
        // zero pad rows 264..277 (bytes [16896, 17792))
        if (tid < 224) ((u32*)(smem + 16896))[tid] = 0u;
    }

    __syncthreads();   // s0: xs_t + b2 slab ready

    // ================= Conv GEMM (operand-swapped => C^T layout) ====================
    floatx4 cacc[9];
    #pragma unroll
    for (int n = 0; n < 9; ++n) {
        const int tt = w + 4 * n;
        if (tt < 34) {
            const int tm = tt >> 1, tn = tt & 1;
            short8 af[3];
            #pragma unroll
            for (int qk = 0; qk < 3; ++qk)
                af[qk] = *(const short8*)(smem + xsw(tm * 16 + l15 + 3 * qk, l4 * 16));
            floatx4 acc = {cbq[tn].x, cbq[tn].y, cbq[tn].z, cbq[tn].w};
            #pragma unroll
            for (int qk = 0; qk < 3; ++qk)
                acc = __builtin_amdgcn_mfma_f32_16x16x32_bf16(b1f[tn][qk], af[qk], acc, 0, 0, 0);
            cacc[n] = acc;
        }
    }
    __syncthreads();   // s1: conv reads done; xs_t dead

    // ---- conv epilogue: cvt_pk pair + one 8-B store per tile, swizzled ----
    #pragma unroll
    for (int n = 0; n < 9; ++n) {
        const int tt = w + 4 * n;
        if (tt < 34) {
            const int tm = tt >> 1, tn = tt & 1;
            const int c_out = tm * 16 + l15;
            const int p = t0 - 1 + c_out;
            u32 q0 = 0u, q1 = 0u;
            if ((unsigned)p < (unsigned)LEN) {
                q0 = cvtpk(leaky(cacc[n][0]), leaky(cacc[n][1]));
                q1 = cvtpk(leaky(cacc[n][2]), leaky(cacc[n][3]));
            }
            *(uint2*)(smem + xsw(c_out, tn * 32 + l4 * 8)) = make_uint2(q0, q1);
        }
    }
    __syncthreads();   // s2: ys_t ready (last barrier)

    // ======= LVC GEMM fused with output: gate(f32) + h + store, all in regs ========
    // Lane owns ch = pp*16+l15 (sigmoid half; +32 is tanh half), positions
    // t*64 + w*16 + l4*4 + {0..3} for t=0..3 -- tiles [t0, t0+256) exactly.
    // h prefetch issued at top of each pp-iteration, hidden under 12 MFMAs.
    #pragma unroll
    for (int pp = 0; pp < 2; ++pp) {
        const int oA = pp * 16 + l15, oB = oA + 32;
        // h prefetch (4 x float4, named -> registers; 16 full lines per instr)
        const float* hrow = hb + (size_t)oA * LEN + t0 + w * 16 + l4 * 4;
        const float4 h0 = *(const float4*)(hrow);
        const float4 h1 = *(const float4*)(hrow + 64);
        const float4 h2 = *(const float4*)(hrow + 128);
        const float4 h3 = *(const float4*)(hrow + 192);
        short8 b2A[3], b2B[3];
        #pragma unroll
        for (int qk = 0; qk < 3; ++qk) {
            b2A[qk] = *(const short8*)(smem + WOFF + oA * WROW + (qk * 32 + l4 * 8) * 2);
            b2B[qk] = *(const short8*)(smem + WOFF + oB * WROW + (qk * 32 + l4 * 8) * 2);
        }
        const float bA = bv[pp][0], bB = bv[pp][1];
        float* orow = out + ((size_t)b * HID + oA) * LEN + t0 + w * 16 + l4 * 4;
#define LVC_T(T, HV)                                                            \
        {                                                                       \
            const int tm = 4 * (T) + w;                                         \
            short8 af0 = *(const short8*)(smem + xsw(tm * 16 + l15,     l4 * 16)); \
            short8 af1 = *(const short8*)(smem + xsw(tm * 16 + l15 + 1, l4 * 16)); \
            short8 af2 = *(const short8*)(smem + xsw(tm * 16 + l15 + 2, l4 * 16)); \
            floatx4 aA = {bA, bA, bA, bA}, aB = {bB, bB, bB, bB};               \
            aA = __builtin_amdgcn_mfma_f32_16x16x32_bf16(af0, b2A[0], aA, 0, 0, 0); \
            aB = __builtin_amdgcn_mfma_f32_16x16x32_bf16(af0, b2B[0], aB, 0, 0, 0); \
            aA = __builtin_amdgcn_mfma_f32_16x16x32_bf16(af1, b2A[1], aA, 0, 0, 0); \
            aB = __builtin_amdgcn_mfma_f32_16x16x32_bf16(af1, b2B[1], aB, 0, 0, 0); \
            aA = __builtin_amdgcn_mfma_f32_16x16x32_bf16(af2, b2A[2], aA, 0, 0, 0); \
            aB = __builtin_amdgcn_mfma_f32_16x16x32_bf16(af2, b2B[2], aB, 0, 0, 0); \
            float4 ov;                                                          \
            ov.x = HV.x + gatef(aA[0], aB[0]);                                  \
            ov.y = HV.y + gatef(aA[1], aB[1]);                                  \
            ov.z = HV.z + gatef(aA[2], aB[2]);                                  \
            ov.w = HV.w + gatef(aA[3], aB[3]);                                  \
            *(float4*)(orow + (T) * 64) = ov;                                   \
        }
        LVC_T(0, h0)
        LVC_T(1, h1)
        LVC_T(2, h2)
        LVC_T(3, h3)
#undef LVC_T
    }
    // kernel ends: stores fire-and-forget, no tail barrier
}

extern "C" void kernel_launch(void* const* d_in, const int* in_sizes, int n_in,
                              void* d_out, int out_size, void* d_ws, size_t ws_size,
                              hipStream_t stream) {
    const float* h    = (const float*)d_in[0];
    const float* kern = (const float*)d_in[1];
    const float* bias = (const float*)d_in[2];
    const float* cw   = (const float*)d_in[3];
    const float* cb   = (const float*)d_in[4];
    float* outp = (float*)d_out;
    unsigned short* kt = (unsigned short*)d_ws;   // ~26.1 MB workspace

    prep_kern<<<1024, 256, 0, stream>>>(kern, cw, kt);
    univnet_mfma<<<2048, 256, 0, stream>>>(h, bias, cb, outp, kt);
}